// Round 5
// baseline (140.809 us; speedup 1.0000x reference)
//
#include <hip/hip_runtime.h>
#include <hip/hip_cooperative_groups.h>

namespace cg = cooperative_groups;

#define NF 39
#define NE 40
#define NB 4096
#define NSLOT 1536            // 6 tiles * 256 accumulator slots
#define NBLK 512
#define SPW 2                 // samples per wave
#define SPB 8                 // samples per block
#define P2_BLOCKS 96          // phase-2 active blocks (96*32 = 3072 cols)
#define EPS 1.0e-3f

typedef __attribute__((ext_vector_type(8))) short short8;
typedef __attribute__((ext_vector_type(4))) float floatx4;

__device__ __forceinline__ unsigned int f2bf(float f) {
    unsigned int b = __float_as_uint(f);
    b += 0x7FFFu + ((b >> 16) & 1u);   // round-to-nearest-even
    return b >> 16;
}

__device__ __forceinline__ short8 pack8(float4 a, float4 b) {
    union { unsigned int u[4]; short8 s; } o;
    o.u[0] = f2bf(a.x) | (f2bf(a.y) << 16);
    o.u[1] = f2bf(a.z) | (f2bf(a.w) << 16);
    o.u[2] = f2bf(b.x) | (f2bf(b.y) << 16);
    o.u[3] = f2bf(b.z) | (f2bf(b.w) << 16);
    return o.s;
}

// Direct-to-register fragment gather for one sample (validated R4).
__device__ __forceinline__ void load_frags(
    const int* __restrict__ ip, const float* __restrict__ v,
    int rbase, int ehalf, short8 F0[3], short8 F1[3])
{
    const float4 zero4 = {0.f, 0.f, 0.f, 0.f};
#pragma unroll
    for (int I = 0; I < 3; ++I) {
        const int r = rbase + 16 * I;
        const bool vr = (r < NF);
        const int id = vr ? ip[r] : 0;
        const float* vrow = v + (size_t)id * NE;
        const float4 a  = vr ? *reinterpret_cast<const float4*>(vrow + ehalf * 8)     : zero4;
        const float4 bq = vr ? *reinterpret_cast<const float4*>(vrow + ehalf * 8 + 4) : zero4;
        F0[I] = pack8(a, bq);
        const bool v1 = vr && (ehalf == 0);
        const float4 c_ = v1 ? *reinterpret_cast<const float4*>(vrow + 32) : zero4;
        const float4 d_ = v1 ? *reinterpret_cast<const float4*>(vrow + 36) : zero4;
        F1[I] = pack8(c_, d_);
    }
}

__device__ __forceinline__ void gram_mfma(const short8 F0[3], const short8 F1[3], floatx4 acc[6])
{
    acc[0] = __builtin_amdgcn_mfma_f32_16x16x32_bf16(F0[0], F0[0], acc[0], 0, 0, 0);
    acc[1] = __builtin_amdgcn_mfma_f32_16x16x32_bf16(F0[0], F0[1], acc[1], 0, 0, 0);
    acc[2] = __builtin_amdgcn_mfma_f32_16x16x32_bf16(F0[0], F0[2], acc[2], 0, 0, 0);
    acc[3] = __builtin_amdgcn_mfma_f32_16x16x32_bf16(F0[1], F0[1], acc[3], 0, 0, 0);
    acc[4] = __builtin_amdgcn_mfma_f32_16x16x32_bf16(F0[1], F0[2], acc[4], 0, 0, 0);
    acc[5] = __builtin_amdgcn_mfma_f32_16x16x32_bf16(F0[2], F0[2], acc[5], 0, 0, 0);
    acc[0] = __builtin_amdgcn_mfma_f32_16x16x32_bf16(F1[0], F1[0], acc[0], 0, 0, 0);
    acc[1] = __builtin_amdgcn_mfma_f32_16x16x32_bf16(F1[0], F1[1], acc[1], 0, 0, 0);
    acc[2] = __builtin_amdgcn_mfma_f32_16x16x32_bf16(F1[0], F1[2], acc[2], 0, 0, 0);
    acc[3] = __builtin_amdgcn_mfma_f32_16x16x32_bf16(F1[1], F1[1], acc[3], 0, 0, 0);
    acc[4] = __builtin_amdgcn_mfma_f32_16x16x32_bf16(F1[1], F1[2], acc[4], 0, 0, 0);
    acc[5] = __builtin_amdgcn_mfma_f32_16x16x32_bf16(F1[2], F1[2], acc[5], 0, 0, 0);
}

__global__ __launch_bounds__(256, 2) void fm_all(
    const int* __restrict__ inputs, const float* __restrict__ w,
    const float* __restrict__ v, const float* __restrict__ ew,
    const float* __restrict__ bias, float* __restrict__ partial,
    float* __restrict__ colsum, float* __restrict__ out)
{
    __shared__ float red[4 * 2 * NSLOT];   // 48 KB
    const int t = threadIdx.x, wid = t >> 6, lane = t & 63;
    const int rbase = lane & 15, ehalf = lane >> 4;
    const int b0 = blockIdx.x * SPB;

    // ---------- Phase 1: gather + Gram + block stats ----------
    floatx4 acc[SPW][6] = {};
    float   wsum[SPW];
    floatx4 sum[6] = {}, sq[6] = {};
#pragma unroll
    for (int s = 0; s < SPW; ++s) {
        const int* ip = inputs + (size_t)(b0 + wid * SPW + s) * NF;
        short8 F0[3], F1[3];
        load_frags(ip, v, rbase, ehalf, F0, F1);
        gram_mfma(F0, F1, acc[s]);
        wsum[s] = (lane < NF) ? w[ip[lane]] : 0.0f;
#pragma unroll
        for (int tl = 0; tl < 6; ++tl) {
            sum[tl] += acc[s][tl];
            sq[tl]  += acc[s][tl] * acc[s][tl];
        }
    }
    float* rw = &red[wid * 2 * NSLOT];
#pragma unroll
    for (int tl = 0; tl < 6; ++tl) {
        *reinterpret_cast<floatx4*>(rw + tl * 256 + lane * 4)         = sum[tl];
        *reinterpret_cast<floatx4*>(rw + NSLOT + tl * 256 + lane * 4) = sq[tl];
    }
    __syncthreads();
    float* po = partial + (size_t)blockIdx.x * (2 * NSLOT);
    for (int j = t; j < 2 * NSLOT; j += 256)
        po[j] = red[j] + red[2 * NSLOT + j] + red[4 * NSLOT + j] + red[6 * NSLOT + j];

    cg::this_grid().sync();

    // ---------- Phase 2: column reduce over 512 partial rows (96 blocks) ----------
    if (blockIdx.x < P2_BLOCKS) {
        const int col = blockIdx.x * 32 + (t & 31);
        const int rg  = t >> 5;                 // 0..7, 64 rows each
        float s = 0.0f;
#pragma unroll 8
        for (int r = 0; r < 64; ++r)
            s += partial[(size_t)(rg * 64 + r) * (2 * NSLOT) + col];
        __syncthreads();                        // red[] dead since phase-1 write-out
        red[t] = s;
        __syncthreads();
        if (t < 32) {
            float tot = 0.0f;
#pragma unroll
            for (int g = 0; g < 8; ++g) tot += red[g * 32 + t];
            colsum[blockIdx.x * 32 + t] = tot;
        }
    }

    cg::this_grid().sync();

    // ---------- Phase 3: per-lane stats finalize + normalize in-reg accs ----------
    const int TI[6] = {0, 0, 0, 1, 1, 2};
    const int TJ[6] = {0, 1, 2, 1, 2, 2};
    float mArr[6][4], sArr[6][4];
#pragma unroll
    for (int tl = 0; tl < 6; ++tl) {
        const floatx4 s1 = *reinterpret_cast<const floatx4*>(colsum + tl * 256 + lane * 4);
        const floatx4 s2 = *reinterpret_cast<const floatx4*>(colsum + NSLOT + tl * 256 + lane * 4);
#pragma unroll
        for (int q = 0; q < 4; ++q) {
            const float m   = s1[q] * (1.0f / NB);
            const float var = s2[q] * (1.0f / NB) - m * m;
            const int gi = 16 * TI[tl] + ehalf * 4 + q;
            const int gj = 16 * TJ[tl] + rbase;
            float scl = 0.0f;
            if (gi < gj && gj < NF) {
                const int p = 38 * gi - (gi * (gi - 1)) / 2 + (gj - gi - 1);
                scl = ew[p] * rsqrtf(var + EPS);
            }
            mArr[tl][q] = m;
            sArr[tl][q] = scl;
        }
    }
    const float bs = bias[0];
#pragma unroll
    for (int s = 0; s < SPW; ++s) {
        float tot = wsum[s];
#pragma unroll
        for (int tl = 0; tl < 6; ++tl)
#pragma unroll
            for (int q = 0; q < 4; ++q)
                tot += (acc[s][tl][q] - mArr[tl][q]) * sArr[tl][q];
#pragma unroll
        for (int o = 32; o > 0; o >>= 1) tot += __shfl_down(tot, o, 64);
        if (lane == 0) out[b0 + wid * SPW + s] = tot + bs;
    }
}

extern "C" void kernel_launch(void* const* d_in, const int* in_sizes, int n_in,
                              void* d_out, int out_size, void* d_ws, size_t ws_size,
                              hipStream_t stream)
{
    const int*   inputs = (const int*)  d_in[0];
    // d_in[1]=rows, d_in[2]=cols reproduced in-kernel (validated R2-R4)
    const float* w      = (const float*)d_in[3];
    const float* v      = (const float*)d_in[4];
    const float* bias   = (const float*)d_in[5];
    const float* ew     = (const float*)d_in[6];
    float*       out    = (float*)      d_out;

    // ws (floats): partial[512*3072] | colsum[3072]
    float* partial = (float*)d_ws;
    float* colsum  = partial + (size_t)NBLK * 2 * NSLOT;

    void* args[] = {(void*)&inputs, (void*)&w, (void*)&v, (void*)&ew,
                    (void*)&bias, (void*)&partial, (void*)&colsum, (void*)&out};
    hipLaunchCooperativeKernel((const void*)fm_all, dim3(NBLK), dim3(256),
                               args, 0, stream);
}

// Round 6
// 32.405 us; speedup vs baseline: 4.3453x; 4.3453x over previous
//
#include <hip/hip_runtime.h>

#define NF 39
#define NE 40
#define NB 4096
#define NSLOT 1536            // 6 tiles * 256 accumulator slots
#define NBLK 512
#define SPW 2                 // samples per wave
#define SPB 8                 // samples per block (4 waves * SPW)
#define K2_BLOCKS 48          // 48 * 32 slots = 1536
#define EPS 1.0e-3f

typedef __attribute__((ext_vector_type(8))) short short8;
typedef __attribute__((ext_vector_type(4))) float floatx4;

__device__ __forceinline__ unsigned int f2bf(float f) {
    unsigned int b = __float_as_uint(f);
    b += 0x7FFFu + ((b >> 16) & 1u);   // round-to-nearest-even
    return b >> 16;
}

__device__ __forceinline__ short8 pack8(float4 a, float4 b) {
    union { unsigned int u[4]; short8 s; } o;
    o.u[0] = f2bf(a.x) | (f2bf(a.y) << 16);
    o.u[1] = f2bf(a.z) | (f2bf(a.w) << 16);
    o.u[2] = f2bf(b.x) | (f2bf(b.y) << 16);
    o.u[3] = f2bf(b.z) | (f2bf(b.w) << 16);
    return o.s;
}

// Direct-to-register fragment gather for one sample (validated R4).
__device__ __forceinline__ void load_frags(
    const int* __restrict__ ip, const float* __restrict__ v,
    int rbase, int ehalf, short8 F0[3], short8 F1[3])
{
    const float4 zero4 = {0.f, 0.f, 0.f, 0.f};
#pragma unroll
    for (int I = 0; I < 3; ++I) {
        const int r = rbase + 16 * I;
        const bool vr = (r < NF);
        const int id = vr ? ip[r] : 0;
        const float* vrow = v + (size_t)id * NE;
        const float4 a  = vr ? *reinterpret_cast<const float4*>(vrow + ehalf * 8)     : zero4;
        const float4 bq = vr ? *reinterpret_cast<const float4*>(vrow + ehalf * 8 + 4) : zero4;
        F0[I] = pack8(a, bq);
        const bool v1 = vr && (ehalf == 0);
        const float4 c_ = v1 ? *reinterpret_cast<const float4*>(vrow + 32) : zero4;
        const float4 d_ = v1 ? *reinterpret_cast<const float4*>(vrow + 36) : zero4;
        F1[I] = pack8(c_, d_);
    }
}

__device__ __forceinline__ void gram_mfma(const short8 F0[3], const short8 F1[3], floatx4 acc[6])
{
    acc[0] = __builtin_amdgcn_mfma_f32_16x16x32_bf16(F0[0], F0[0], acc[0], 0, 0, 0);
    acc[1] = __builtin_amdgcn_mfma_f32_16x16x32_bf16(F0[0], F0[1], acc[1], 0, 0, 0);
    acc[2] = __builtin_amdgcn_mfma_f32_16x16x32_bf16(F0[0], F0[2], acc[2], 0, 0, 0);
    acc[3] = __builtin_amdgcn_mfma_f32_16x16x32_bf16(F0[1], F0[1], acc[3], 0, 0, 0);
    acc[4] = __builtin_amdgcn_mfma_f32_16x16x32_bf16(F0[1], F0[2], acc[4], 0, 0, 0);
    acc[5] = __builtin_amdgcn_mfma_f32_16x16x32_bf16(F0[2], F0[2], acc[5], 0, 0, 0);
    acc[0] = __builtin_amdgcn_mfma_f32_16x16x32_bf16(F1[0], F1[0], acc[0], 0, 0, 0);
    acc[1] = __builtin_amdgcn_mfma_f32_16x16x32_bf16(F1[0], F1[1], acc[1], 0, 0, 0);
    acc[2] = __builtin_amdgcn_mfma_f32_16x16x32_bf16(F1[0], F1[2], acc[2], 0, 0, 0);
    acc[3] = __builtin_amdgcn_mfma_f32_16x16x32_bf16(F1[1], F1[1], acc[3], 0, 0, 0);
    acc[4] = __builtin_amdgcn_mfma_f32_16x16x32_bf16(F1[1], F1[2], acc[4], 0, 0, 0);
    acc[5] = __builtin_amdgcn_mfma_f32_16x16x32_bf16(F1[2], F1[2], acc[5], 0, 0, 0);
}

// ---------------- Kernel 1: gather once -> store frags + Gram stats + lsum ----------------
__global__ __launch_bounds__(256) void fm_k1(
    const int* __restrict__ inputs, const float* __restrict__ w,
    const float* __restrict__ v, short8* __restrict__ wf0,
    short8* __restrict__ wf1, float* __restrict__ lsum,
    float* __restrict__ partial)
{
    __shared__ float red[4 * 2 * NSLOT];   // 48 KB cross-wave stats fold
    const int t = threadIdx.x, wid = t >> 6, lane = t & 63;
    const int rbase = lane & 15, ehalf = lane >> 4;
    const int b0 = blockIdx.x * SPB;

    floatx4 sum[6] = {}, sq[6] = {};
#pragma unroll
    for (int s = 0; s < SPW; ++s) {
        const int smp = b0 + wid * SPW + s;
        const int* ip = inputs + (size_t)smp * NF;
        short8 F0[3], F1[3];
        load_frags(ip, v, rbase, ehalf, F0, F1);
        // persist fragments (coalesced): F0 full, F1 only ehalf==0 lanes (rest are zeros)
#pragma unroll
        for (int I = 0; I < 3; ++I) {
            wf0[((size_t)smp * 3 + I) * 64 + lane] = F0[I];
            if (ehalf == 0) wf1[((size_t)smp * 3 + I) * 16 + rbase] = F1[I];
        }
        // first-order term
        float wv = (lane < NF) ? w[ip[lane]] : 0.0f;
#pragma unroll
        for (int o = 32; o > 0; o >>= 1) wv += __shfl_down(wv, o, 64);
        if (lane == 0) lsum[smp] = wv;

        floatx4 acc[6] = {};
        gram_mfma(F0, F1, acc);
#pragma unroll
        for (int tl = 0; tl < 6; ++tl) {
            sum[tl] += acc[tl];
            sq[tl]  += acc[tl] * acc[tl];
        }
    }

    float* rw = &red[wid * 2 * NSLOT];
#pragma unroll
    for (int tl = 0; tl < 6; ++tl) {
        *reinterpret_cast<floatx4*>(rw + tl * 256 + lane * 4)         = sum[tl];
        *reinterpret_cast<floatx4*>(rw + NSLOT + tl * 256 + lane * 4) = sq[tl];
    }
    __syncthreads();
    float* po = partial + (size_t)blockIdx.x * (2 * NSLOT);
    for (int j = t; j < 2 * NSLOT; j += 256)
        po[j] = red[j] + red[2 * NSLOT + j] + red[4 * NSLOT + j] + red[6 * NSLOT + j];
}

// ---------------- Kernel 2: fused column-reduce + mean/scale finalize ----------------
__global__ __launch_bounds__(256) void fm_k2(
    const float* __restrict__ partial, const float* __restrict__ ew,
    float* __restrict__ meanArr, float* __restrict__ scaleArr)
{
    const int t = threadIdx.x;
    const int slotL = t & 31, rg = t >> 5;          // 8 row-groups x 64 rows
    const int slot0 = blockIdx.x * 32;
    float s1 = 0.f, s2 = 0.f;
#pragma unroll 8
    for (int r = 0; r < 64; ++r) {
        const float* row = partial + (size_t)(rg * 64 + r) * (2 * NSLOT);
        s1 += row[slot0 + slotL];
        s2 += row[NSLOT + slot0 + slotL];
    }
    __shared__ float r1[8][32], r2[8][32];
    r1[rg][slotL] = s1;
    r2[rg][slotL] = s2;
    __syncthreads();
    if (t < 32) {
        float a = 0.f, b = 0.f;
#pragma unroll
        for (int g = 0; g < 8; ++g) { a += r1[g][t]; b += r2[g][t]; }
        const int slot = slot0 + t;
        const float m   = a * (1.0f / NB);
        const float var = b * (1.0f / NB) - m * m;
        const int tile = slot >> 8;
        const int l    = (slot & 255) >> 2;
        const int q    = slot & 3;
        const int TI[6] = {0, 0, 0, 1, 1, 2};
        const int TJ[6] = {0, 1, 2, 1, 2, 2};
        const int gi = 16 * TI[tile] + ((l >> 4) << 2) + q;
        const int gj = 16 * TJ[tile] + (l & 15);
        float scl = 0.0f;
        if (gi < gj && gj < NF) {
            const int p = 38 * gi - (gi * (gi - 1)) / 2 + (gj - gi - 1);
            scl = ew[p] * rsqrtf(var + EPS);
        }
        meanArr[slot]  = m;
        scaleArr[slot] = scl;
    }
}

// ---------------- Kernel 3: stream frags + Gram + normalize-reduce ----------------
__global__ __launch_bounds__(256) void fm_k3(
    const short8* __restrict__ wf0, const short8* __restrict__ wf1,
    const float* __restrict__ lsum, const float* __restrict__ meanArr,
    const float* __restrict__ scaleArr, const float* __restrict__ bias,
    float* __restrict__ out)
{
    const int t = threadIdx.x, wid = t >> 6, lane = t & 63;
    const int rbase = lane & 15, ehalf = lane >> 4;
    const int b0 = blockIdx.x * SPB;

    floatx4 mf[6], sf[6];
#pragma unroll
    for (int tl = 0; tl < 6; ++tl) {
        mf[tl] = *reinterpret_cast<const floatx4*>(meanArr  + tl * 256 + lane * 4);
        sf[tl] = *reinterpret_cast<const floatx4*>(scaleArr + tl * 256 + lane * 4);
    }
    const float bs = bias[0];
    const short8 z8 = {0, 0, 0, 0, 0, 0, 0, 0};

#pragma unroll
    for (int s = 0; s < SPW; ++s) {
        const int smp = b0 + wid * SPW + s;
        short8 F0[3], F1[3];
#pragma unroll
        for (int I = 0; I < 3; ++I) {
            F0[I] = wf0[((size_t)smp * 3 + I) * 64 + lane];
            F1[I] = (ehalf == 0) ? wf1[((size_t)smp * 3 + I) * 16 + rbase] : z8;
        }
        floatx4 acc[6] = {};
        gram_mfma(F0, F1, acc);
        float tot = (lane == 0) ? lsum[smp] : 0.0f;
#pragma unroll
        for (int tl = 0; tl < 6; ++tl)
#pragma unroll
            for (int q = 0; q < 4; ++q)
                tot += (acc[tl][q] - mf[tl][q]) * sf[tl][q];
#pragma unroll
        for (int o = 32; o > 0; o >>= 1) tot += __shfl_down(tot, o, 64);
        if (lane == 0) out[smp] = tot + bs;
    }
}

extern "C" void kernel_launch(void* const* d_in, const int* in_sizes, int n_in,
                              void* d_out, int out_size, void* d_ws, size_t ws_size,
                              hipStream_t stream)
{
    const int*   inputs = (const int*)  d_in[0];
    // d_in[1]=rows, d_in[2]=cols reproduced in-kernel (validated R2-R5)
    const float* w      = (const float*)d_in[3];
    const float* v      = (const float*)d_in[4];
    const float* bias   = (const float*)d_in[5];
    const float* ew     = (const float*)d_in[6];
    float*       out    = (float*)      d_out;

    // ws layout: wf0[4096*3*64 short8] | wf1[4096*3*16 short8] | floats: partial[512*3072] | mean | scale | lsum
    short8* wf0 = (short8*)d_ws;
    short8* wf1 = wf0 + (size_t)NB * 3 * 64;
    float* partial = (float*)(wf1 + (size_t)NB * 3 * 16);
    float* meanA   = partial + (size_t)NBLK * 2 * NSLOT;
    float* scaleA  = meanA + NSLOT;
    float* lsum    = scaleA + NSLOT;

    fm_k1<<<NBLK,      256, 0, stream>>>(inputs, w, v, wf0, wf1, lsum, partial);
    fm_k2<<<K2_BLOCKS, 256, 0, stream>>>(partial, ew, meanA, scaleA);
    fm_k3<<<NBLK,      256, 0, stream>>>(wf0, wf1, lsum, meanA, scaleA, bias, out);
}